// Round 5
// baseline (547.585 us; speedup 1.0000x reference)
//
#include <hip/hip_runtime.h>
#include <stdint.h>

#define BB 9            // bucket = dst >> 9 (512 dsts per bucket)
#define BSZ 512
#define STAGE_CAP 12288 // bucket edge capacity (mean ~8192, +45 sigma margin)

// ---------------------------------------------------------------------------
__global__ void fill_zero_i4(int4* __restrict__ p, size_t n4) {
    size_t i = (size_t)blockIdx.x * blockDim.x + threadIdx.x;
    size_t stride = (size_t)gridDim.x * blockDim.x;
    for (; i < n4; i += stride) p[i] = make_int4(0, 0, 0, 0);
}

// ---------------------------------------------------------------------------
// K1: coarse-bucket histogram, LDS-aggregated. Both relations in one grid.
__global__ void khist(const int* __restrict__ e1, const int* __restrict__ e2, int E,
                      int* __restrict__ gcnt1, int* __restrict__ gcnt2,
                      int nb1, int nb2, int blocksPerRel) {
    int rel = blockIdx.x >= blocksPerRel;
    int blk = rel ? blockIdx.x - blocksPerRel : blockIdx.x;
    const int* dst = (rel ? e2 : e1) + E;
    int* gcnt = rel ? gcnt2 : gcnt1;
    int nb = rel ? nb2 : nb1;
    __shared__ int cnt[256];
    for (int i = threadIdx.x; i < 256; i += 256) cnt[i] = 0;
    __syncthreads();
    int base = blk * 8192;
#pragma unroll
    for (int k = 0; k < 32; k++) {
        int i = base + k * 256 + threadIdx.x;
        if (i < E) atomicAdd(&cnt[dst[i] >> BB], 1);
    }
    __syncthreads();
    for (int b = threadIdx.x; b < nb; b += 256)
        if (cnt[b]) atomicAdd(&gcnt[b], cnt[b]);
}

// ---------------------------------------------------------------------------
// K2: exclusive scan of bucket counts (nb <= 256) -> boff[nb+1], gcur=boff.
__global__ void kscan(const int* __restrict__ gcnt1, int* __restrict__ boff1,
                      int* __restrict__ gcur1, int nb1,
                      const int* __restrict__ gcnt2, int* __restrict__ boff2,
                      int* __restrict__ gcur2, int nb2, int E) {
    const int* gcnt = blockIdx.x ? gcnt2 : gcnt1;
    int* boff = blockIdx.x ? boff2 : boff1;
    int* gcur = blockIdx.x ? gcur2 : gcur1;
    int nb = blockIdx.x ? nb2 : nb1;
    __shared__ int wsum[4];
    int tid = threadIdx.x, lane = tid & 63, wid = tid >> 6;
    int v = (tid < nb) ? gcnt[tid] : 0;
    int sc = v;
#pragma unroll
    for (int off = 1; off < 64; off <<= 1) {
        int t = __shfl_up(sc, off, 64);
        if (lane >= off) sc += t;
    }
    if (lane == 63) wsum[wid] = sc;
    __syncthreads();
    int woff = 0;
    for (int w = 0; w < wid; w++) woff += wsum[w];
    int excl = woff + sc - v;
    if (tid < nb) { boff[tid] = excl; gcur[tid] = excl; }
    if (tid == nb - 1) boff[nb] = excl + v;  // == E
}

// ---------------------------------------------------------------------------
// K3: bin edges into bucket regions (packed (src<<9 | dst&511) u32 runs).
__global__ void kbin(const int* __restrict__ e1, const int* __restrict__ e2, int E,
                     int* __restrict__ gcur1, int* __restrict__ gcur2,
                     unsigned int* __restrict__ P1, unsigned int* __restrict__ P2,
                     int blocksPerRel) {
    int rel = blockIdx.x >= blocksPerRel;
    int blk = rel ? blockIdx.x - blocksPerRel : blockIdx.x;
    const int* edge = rel ? e2 : e1;
    int* gcur = rel ? gcur2 : gcur1;
    unsigned int* P = rel ? P2 : P1;
    __shared__ int cnt[256];
    __shared__ int base[256];
    for (int i = threadIdx.x; i < 256; i += 256) cnt[i] = 0;
    __syncthreads();
    int cbase = blk * 4096;
    int src[16], dst[16], rk[16];
#pragma unroll
    for (int k = 0; k < 16; k++) {
        int i = cbase + k * 256 + threadIdx.x;
        if (i < E) {
            src[k] = edge[i];
            dst[k] = edge[E + i];
            rk[k] = atomicAdd(&cnt[dst[k] >> BB], 1);
        }
    }
    __syncthreads();
    for (int b = threadIdx.x; b < 256; b += 256)
        base[b] = cnt[b] ? atomicAdd(&gcur[b], cnt[b]) : 0;
    __syncthreads();
#pragma unroll
    for (int k = 0; k < 16; k++) {
        int i = cbase + k * 256 + threadIdx.x;
        if (i < E) {
            int b = dst[k] >> BB;
            P[base[b] + rk[k]] =
                ((unsigned)src[k] << BB) | (unsigned)(dst[k] & (BSZ - 1));
        }
    }
}

// ---------------------------------------------------------------------------
// K4: per-bucket counting sort in LDS -> sorted srcs + CSR row offsets.
__global__ void kbsort(const unsigned int* __restrict__ P1, const unsigned int* __restrict__ P2,
                       const int* __restrict__ boff1, const int* __restrict__ boff2,
                       int* __restrict__ ss1, int* __restrict__ ss2,
                       int* __restrict__ ro1, int* __restrict__ ro2,
                       int n1, int n2, int nb1, int nb2, int E) {
    int rel = blockIdx.x >= nb1;
    int b = rel ? blockIdx.x - nb1 : blockIdx.x;
    const unsigned int* P = rel ? P2 : P1;
    const int* boff = rel ? boff2 : boff1;
    int* ss = rel ? ss2 : ss1;
    int* ro = rel ? ro2 : ro1;
    int N = rel ? n2 : n1;
    int nb = rel ? nb2 : nb1;

    __shared__ int cnt[BSZ];
    __shared__ int cur[BSZ];
    __shared__ int wsum[8];
    __shared__ int stage[STAGE_CAP];

    int s = boff[b], e = boff[b + 1];
    int m = e - s;
    int d0 = b << BB;
    int nd = min(BSZ, N - d0);
    int tid = threadIdx.x;

    cnt[tid] = 0;
    __syncthreads();
    for (int i = tid; i < m; i += 512) atomicAdd(&cnt[P[s + i] & (BSZ - 1)], 1);
    __syncthreads();
    int lane = tid & 63, wid = tid >> 6;
    int v = cnt[tid], sc = v;
#pragma unroll
    for (int off = 1; off < 64; off <<= 1) {
        int t = __shfl_up(sc, off, 64);
        if (lane >= off) sc += t;
    }
    if (lane == 63) wsum[wid] = sc;
    __syncthreads();
    int woff = 0;
    for (int w = 0; w < wid; w++) woff += wsum[w];
    int excl = woff + sc - v;
    cur[tid] = excl;
    if (tid < nd) ro[d0 + tid] = s + excl;
    if (tid == 0 && b == nb - 1) ro[N] = E;
    __syncthreads();
    for (int i = tid; i < m; i += 512) {
        unsigned int p = P[s + i];
        int slot = atomicAdd(&cur[p & (BSZ - 1)], 1);
        if (slot < STAGE_CAP) stage[slot] = (int)(p >> BB);
    }
    __syncthreads();
    for (int i = tid; i < m; i += 512) ss[s + i] = stage[i];
}

// ---------------------------------------------------------------------------
// projection y = x @ W  (K -> 32), OutT in {float, _Float16}
template <int K, typename OutT>
__global__ void projK(const float* __restrict__ x, const float* __restrict__ W,
                      OutT* __restrict__ y, int N) {
    int gid = blockIdx.x * blockDim.x + threadIdx.x;
    int node = gid >> 5, od = gid & 31;
    if (node >= N) return;
    const float* xr = x + (size_t)node * K;
    float acc = 0.0f;
#pragma unroll
    for (int k = 0; k < K; k++) acc += xr[k] * W[(k << 5) + od];
    y[((size_t)node << 5) + od] = (OutT)acc;
}

// ---------------------------------------------------------------------------
// merged layer-1 pull (both relations): h = relu(b + s + mean_gather(y))
// y is fp16 (64B row line), self-term s precomputed, 4-wide unrolled gather.
__global__ void pull_l1_both(
    const int* __restrict__ ro_p, const int* __restrict__ ssp, const _Float16* __restrict__ y_c,
    const float* __restrict__ sp, const float* __restrict__ b_p, float* __restrict__ h_p,
    int NP, int blocksP,
    const int* __restrict__ ro_c, const int* __restrict__ ssc, const _Float16* __restrict__ y_p,
    const float* __restrict__ sc_, const float* __restrict__ b_c, float* __restrict__ h_c, int NC) {
    int rel = blockIdx.x >= blocksP;
    int blk = rel ? blockIdx.x - blocksP : blockIdx.x;
    const int* ro = rel ? ro_c : ro_p;
    const int* ss = rel ? ssc : ssp;
    const _Float16* y = rel ? y_p : y_c;
    const float* sf = rel ? sc_ : sp;
    const float* bv = rel ? b_c : b_p;
    float* h = rel ? h_c : h_p;
    int N = rel ? NC : NP;

    int gid = blk * 256 + threadIdx.x;
    int node = gid >> 5, od = gid & 31;
    if (node >= N) return;
    int start = ro[node], end = ro[node + 1];
    float acc = 0.0f;
    int j = start;
    for (; j + 3 < end; j += 4) {
        int a0 = ss[j], a1 = ss[j + 1], a2 = ss[j + 2], a3 = ss[j + 3];
        acc += (float)y[((size_t)a0 << 5) + od] + (float)y[((size_t)a1 << 5) + od]
             + (float)y[((size_t)a2 << 5) + od] + (float)y[((size_t)a3 << 5) + od];
    }
    for (; j < end; j++) acc += (float)y[((size_t)ss[j] << 5) + od];
    float r = bv[od] + sf[((size_t)node << 5) + od]
            + acc / fmaxf((float)(end - start), 1.0f);
    h[((size_t)node << 5) + od] = fmaxf(r, 0.0f);
}

// ---------------------------------------------------------------------------
// layer-2 pull + head: logit = sum_od (mean_gather(z)+b2+s2)*Wlin + blin
__global__ void pull_l2_head(const int* __restrict__ row_off, const int* __restrict__ srcs,
                             const _Float16* __restrict__ z, const float* __restrict__ s2,
                             const float* __restrict__ b2, const float* __restrict__ Wlin,
                             const float* __restrict__ blin,
                             float* __restrict__ out, int N) {
    int gid = blockIdx.x * blockDim.x + threadIdx.x;
    int node = gid >> 5, od = gid & 31;
    float v = 0.0f;
    if (node < N) {
        int start = row_off[node], end = row_off[node + 1];
        float acc = 0.0f;
        int j = start;
        for (; j + 3 < end; j += 4) {
            int a0 = srcs[j], a1 = srcs[j + 1], a2 = srcs[j + 2], a3 = srcs[j + 3];
            acc += (float)z[((size_t)a0 << 5) + od] + (float)z[((size_t)a1 << 5) + od]
                 + (float)z[((size_t)a2 << 5) + od] + (float)z[((size_t)a3 << 5) + od];
        }
        for (; j < end; j++) acc += (float)z[((size_t)srcs[j] << 5) + od];
        float r = acc / fmaxf((float)(end - start), 1.0f) + b2[od]
                + s2[((size_t)node << 5) + od];
        v = r * Wlin[od];
    }
#pragma unroll
    for (int off = 16; off > 0; off >>= 1) v += __shfl_xor(v, off, 32);
    if (node < N && od == 0) {
        float logit = v + blin[0];
        out[node] = 1.0f / (1.0f + expf(-logit));
    }
}

// ---------------------------------------------------------------------------
extern "C" void kernel_launch(void* const* d_in, const int* in_sizes, int n_in,
                              void* d_out, int out_size, void* d_ws, size_t ws_size,
                              hipStream_t stream) {
    const float* xc    = (const float*)d_in[0];
    const float* xp    = (const float*)d_in[1];
    const int*   e_c2p = (const int*)d_in[2];   // src=cust, dst=prod
    const int*   e_p2c = (const int*)d_in[3];   // src=prod, dst=cust
    const float* W1l_r1 = (const float*)d_in[4];
    const float* b1_r1  = (const float*)d_in[5];
    const float* W1r_r1 = (const float*)d_in[6];
    const float* W1l_r2 = (const float*)d_in[7];
    const float* b1_r2  = (const float*)d_in[8];
    const float* W1r_r2 = (const float*)d_in[9];
    const float* W2l_r1 = (const float*)d_in[10];
    const float* b2_r1  = (const float*)d_in[11];
    const float* W2r_r1 = (const float*)d_in[12];
    const float* Wlin  = (const float*)d_in[16];
    const float* blin  = (const float*)d_in[17];
    float* out = (float*)d_out;

    const int NC = in_sizes[0] / 64;
    const int NP = in_sizes[1] / 64;
    const int E  = in_sizes[2] / 2;
    const int nbP = (NP + BSZ - 1) >> BB;
    const int nbC = (NC + BSZ - 1) >> BB;

    // ---- workspace layout ----
    char* w = (char*)d_ws;
    int* gcnt_p = (int*)w;  w += 256 * 4;
    int* gcnt_c = (int*)w;  w += 256 * 4;
    int* gcur_p = (int*)w;  w += 256 * 4;
    int* gcur_c = (int*)w;  w += 256 * 4;
    int* boff_p = (int*)w;  w += 257 * 4;
    int* boff_c = (int*)w;  w += 257 * 4;
    w = (char*)(((uintptr_t)w + 255) & ~(uintptr_t)255);
    size_t szPair = (size_t)E * 4;
    if ((size_t)NP * 64 > szPair) szPair = (size_t)NP * 64;   // fp16 y fits pair buf
    if ((size_t)NC * 64 > szPair) szPair = (size_t)NC * 64;
    unsigned int* P_p = (unsigned int*)w;  w += szPair;   // later: y_c, then z_c
    unsigned int* P_c = (unsigned int*)w;  w += szPair;   // later: y_p
    int* ss_p = (int*)w;    w += (size_t)E * 4;
    int* ss_c = (int*)w;    w += (size_t)E * 4;
    int* ro_p = (int*)w;    w += (size_t)(NP + 1) * 4;
    int* ro_c = (int*)w;    w += (size_t)(NC + 1) * 4;
    w = (char*)(((uintptr_t)w + 255) & ~(uintptr_t)255);
    float* s_p = (float*)w; w += (size_t)NP * 32 * 4;   // xp @ W1r_r1
    float* s_c = (float*)w; w += (size_t)NC * 32 * 4;   // xc @ W1r_r2; later s2_p
    float* h_p = (float*)w; w += (size_t)NP * 32 * 4;
    float* h_c = (float*)w; w += (size_t)NC * 32 * 4;
    _Float16* y_c = (_Float16*)P_p;   // alias (pairs dead after kbsort)
    _Float16* y_p = (_Float16*)P_c;
    _Float16* z_c = y_c;              // alias (y_c dead after pull_l1_both)
    float* s2_p = s_c;                // alias (s_c dead after pull_l1_both)

    const int bprH = (E + 8191) / 8192;
    const int bprB = (E + 4095) / 4096;

    // 1. zero bucket histograms
    fill_zero_i4<<<1, 128, 0, stream>>>((int4*)gcnt_p, 128);

    // 2-5. CSR build
    khist<<<2 * bprH, 256, 0, stream>>>(e_c2p, e_p2c, E, gcnt_p, gcnt_c, nbP, nbC, bprH);
    kscan<<<2, 256, 0, stream>>>(gcnt_p, boff_p, gcur_p, nbP, gcnt_c, boff_c, gcur_c, nbC, E);
    kbin<<<2 * bprB, 256, 0, stream>>>(e_c2p, e_p2c, E, gcur_p, gcur_c, P_p, P_c, bprB);
    kbsort<<<nbP + nbC, 512, 0, stream>>>(P_p, P_c, boff_p, boff_c,
                                          ss_p, ss_c, ro_p, ro_c, NP, NC, nbP, nbC, E);

    // 6. projections: aggregation operands (fp16) + self-terms (fp32)
    projK<64, _Float16><<<(NC * 32 + 255) / 256, 256, 0, stream>>>(xc, W1l_r1, y_c, NC);
    projK<64, _Float16><<<(NP * 32 + 255) / 256, 256, 0, stream>>>(xp, W1l_r2, y_p, NP);
    projK<64, float><<<(NP * 32 + 255) / 256, 256, 0, stream>>>(xp, W1r_r1, s_p, NP);
    projK<64, float><<<(NC * 32 + 255) / 256, 256, 0, stream>>>(xc, W1r_r2, s_c, NC);

    // 7. merged layer-1 pulls
    const int blocksP = (NP * 32 + 255) / 256;
    const int blocksC = (NC * 32 + 255) / 256;
    pull_l1_both<<<blocksP + blocksC, 256, 0, stream>>>(
        ro_p, ss_p, y_c, s_p, b1_r1, h_p, NP, blocksP,
        ro_c, ss_c, y_p, s_c, b1_r2, h_c, NC);

    // 8. layer-2 projections (aliases safe: y_c/s_c dead)
    projK<32, _Float16><<<(NC * 32 + 255) / 256, 256, 0, stream>>>(h_c, W2l_r1, z_c, NC);
    projK<32, float><<<(NP * 32 + 255) / 256, 256, 0, stream>>>(h_p, W2r_r1, s2_p, NP);

    // 9. layer-2 pull + head + sigmoid (reuses c2p CSR)
    pull_l2_head<<<blocksP, 256, 0, stream>>>(
        ro_p, ss_p, z_c, s2_p, b2_r1, Wlin, blin, out, NP);
}

// Round 6
// 412.849 us; speedup vs baseline: 1.3264x; 1.3264x over previous
//
#include <hip/hip_runtime.h>
#include <stdint.h>

#define BB 9            // bucket = dst >> 9 (512 dsts per bucket)
#define BSZ 512
#define STAGE_CAP 12288 // bucket edge capacity (mean ~8192, +45 sigma margin)

// ---------------------------------------------------------------------------
__global__ void fill_zero_i4(int4* __restrict__ p, size_t n4) {
    size_t i = (size_t)blockIdx.x * blockDim.x + threadIdx.x;
    size_t stride = (size_t)gridDim.x * blockDim.x;
    for (; i < n4; i += stride) p[i] = make_int4(0, 0, 0, 0);
}

// ---------------------------------------------------------------------------
// K1: coarse-bucket histogram, LDS-aggregated. Both relations in one grid.
__global__ void khist(const int* __restrict__ e1, const int* __restrict__ e2, int E,
                      int* __restrict__ gcnt1, int* __restrict__ gcnt2,
                      int nb1, int nb2, int blocksPerRel) {
    int rel = blockIdx.x >= blocksPerRel;
    int blk = rel ? blockIdx.x - blocksPerRel : blockIdx.x;
    const int* dst = (rel ? e2 : e1) + E;
    int* gcnt = rel ? gcnt2 : gcnt1;
    int nb = rel ? nb2 : nb1;
    __shared__ int cnt[256];
    for (int i = threadIdx.x; i < 256; i += 256) cnt[i] = 0;
    __syncthreads();
    int base = blk * 8192;
#pragma unroll
    for (int k = 0; k < 32; k++) {
        int i = base + k * 256 + threadIdx.x;
        if (i < E) atomicAdd(&cnt[dst[i] >> BB], 1);
    }
    __syncthreads();
    for (int b = threadIdx.x; b < nb; b += 256)
        if (cnt[b]) atomicAdd(&gcnt[b], cnt[b]);
}

// ---------------------------------------------------------------------------
// K2: exclusive scan of bucket counts (nb <= 256) -> boff[nb+1], gcur=boff.
__global__ void kscan(const int* __restrict__ gcnt1, int* __restrict__ boff1,
                      int* __restrict__ gcur1, int nb1,
                      const int* __restrict__ gcnt2, int* __restrict__ boff2,
                      int* __restrict__ gcur2, int nb2, int E) {
    const int* gcnt = blockIdx.x ? gcnt2 : gcnt1;
    int* boff = blockIdx.x ? boff2 : boff1;
    int* gcur = blockIdx.x ? gcur2 : gcur1;
    int nb = blockIdx.x ? nb2 : nb1;
    __shared__ int wsum[4];
    int tid = threadIdx.x, lane = tid & 63, wid = tid >> 6;
    int v = (tid < nb) ? gcnt[tid] : 0;
    int sc = v;
#pragma unroll
    for (int off = 1; off < 64; off <<= 1) {
        int t = __shfl_up(sc, off, 64);
        if (lane >= off) sc += t;
    }
    if (lane == 63) wsum[wid] = sc;
    __syncthreads();
    int woff = 0;
    for (int w = 0; w < wid; w++) woff += wsum[w];
    int excl = woff + sc - v;
    if (tid < nb) { boff[tid] = excl; gcur[tid] = excl; }
    if (tid == nb - 1) boff[nb] = excl + v;  // == E
}

// ---------------------------------------------------------------------------
// K3: bin edges into bucket regions (packed (src<<9 | dst&511) u32 runs).
__global__ void kbin(const int* __restrict__ e1, const int* __restrict__ e2, int E,
                     int* __restrict__ gcur1, int* __restrict__ gcur2,
                     unsigned int* __restrict__ P1, unsigned int* __restrict__ P2,
                     int blocksPerRel) {
    int rel = blockIdx.x >= blocksPerRel;
    int blk = rel ? blockIdx.x - blocksPerRel : blockIdx.x;
    const int* edge = rel ? e2 : e1;
    int* gcur = rel ? gcur2 : gcur1;
    unsigned int* P = rel ? P2 : P1;
    __shared__ int cnt[256];
    __shared__ int base[256];
    for (int i = threadIdx.x; i < 256; i += 256) cnt[i] = 0;
    __syncthreads();
    int cbase = blk * 4096;
    int src[16], dst[16], rk[16];
#pragma unroll
    for (int k = 0; k < 16; k++) {
        int i = cbase + k * 256 + threadIdx.x;
        if (i < E) {
            src[k] = edge[i];
            dst[k] = edge[E + i];
            rk[k] = atomicAdd(&cnt[dst[k] >> BB], 1);
        }
    }
    __syncthreads();
    for (int b = threadIdx.x; b < 256; b += 256)
        base[b] = cnt[b] ? atomicAdd(&gcur[b], cnt[b]) : 0;
    __syncthreads();
#pragma unroll
    for (int k = 0; k < 16; k++) {
        int i = cbase + k * 256 + threadIdx.x;
        if (i < E) {
            int b = dst[k] >> BB;
            P[base[b] + rk[k]] =
                ((unsigned)src[k] << BB) | (unsigned)(dst[k] & (BSZ - 1));
        }
    }
}

// ---------------------------------------------------------------------------
// K4: per-bucket counting sort in LDS -> sorted srcs + CSR row offsets.
__global__ void kbsort(const unsigned int* __restrict__ P1, const unsigned int* __restrict__ P2,
                       const int* __restrict__ boff1, const int* __restrict__ boff2,
                       int* __restrict__ ss1, int* __restrict__ ss2,
                       int* __restrict__ ro1, int* __restrict__ ro2,
                       int n1, int n2, int nb1, int nb2, int E) {
    int rel = blockIdx.x >= nb1;
    int b = rel ? blockIdx.x - nb1 : blockIdx.x;
    const unsigned int* P = rel ? P2 : P1;
    const int* boff = rel ? boff2 : boff1;
    int* ss = rel ? ss2 : ss1;
    int* ro = rel ? ro2 : ro1;
    int N = rel ? n2 : n1;
    int nb = rel ? nb2 : nb1;

    __shared__ int cnt[BSZ];
    __shared__ int cur[BSZ];
    __shared__ int wsum[8];
    __shared__ int stage[STAGE_CAP];

    int s = boff[b], e = boff[b + 1];
    int m = e - s;
    int d0 = b << BB;
    int nd = min(BSZ, N - d0);
    int tid = threadIdx.x;

    cnt[tid] = 0;
    __syncthreads();
    for (int i = tid; i < m; i += 512) atomicAdd(&cnt[P[s + i] & (BSZ - 1)], 1);
    __syncthreads();
    int lane = tid & 63, wid = tid >> 6;
    int v = cnt[tid], sc = v;
#pragma unroll
    for (int off = 1; off < 64; off <<= 1) {
        int t = __shfl_up(sc, off, 64);
        if (lane >= off) sc += t;
    }
    if (lane == 63) wsum[wid] = sc;
    __syncthreads();
    int woff = 0;
    for (int w = 0; w < wid; w++) woff += wsum[w];
    int excl = woff + sc - v;
    cur[tid] = excl;
    if (tid < nd) ro[d0 + tid] = s + excl;
    if (tid == 0 && b == nb - 1) ro[N] = E;
    __syncthreads();
    for (int i = tid; i < m; i += 512) {
        unsigned int p = P[s + i];
        int slot = atomicAdd(&cur[p & (BSZ - 1)], 1);
        if (slot < STAGE_CAP) stage[slot] = (int)(p >> BB);
    }
    __syncthreads();
    for (int i = tid; i < m; i += 512) ss[s + i] = stage[i];
}

// ---------------------------------------------------------------------------
// head precompute (D_OUT=1 collapse): v2l = W2l@Wlin, v2r = W2r@Wlin,
// cbias = b2.Wlin + blin.  hconst layout: [0..31]=v2l, [32..63]=v2r, [64]=cbias
__global__ void head_pre(const float* __restrict__ W2l, const float* __restrict__ W2r,
                         const float* __restrict__ b2, const float* __restrict__ Wlin,
                         const float* __restrict__ blin, float* __restrict__ hconst) {
    int t = threadIdx.x;
    if (t < 64) {
        const float* W = (t < 32) ? W2l : W2r;
        int k = t & 31;
        float acc = 0.0f;
#pragma unroll
        for (int j = 0; j < 32; j++) acc += W[k * 32 + j] * Wlin[j];
        hconst[t] = acc;
    }
    if (t == 64) {
        float acc = blin[0];
#pragma unroll
        for (int j = 0; j < 32; j++) acc += b2[j] * Wlin[j];
        hconst[64] = acc;
    }
}

// ---------------------------------------------------------------------------
// fused projection: one pass over x computes y = x@Wy (fp16, gather operand)
// and s = x@Ws (fp32, self-term). Both node types in one grid.
__global__ void proj_fused(
    const float* __restrict__ x1, const float* __restrict__ Wy1, const float* __restrict__ Ws1,
    _Float16* __restrict__ y1, float* __restrict__ s1, int N1, int blocks1,
    const float* __restrict__ x2, const float* __restrict__ Wy2, const float* __restrict__ Ws2,
    _Float16* __restrict__ y2, float* __restrict__ s2, int N2) {
    int rel = blockIdx.x >= blocks1;
    int blk = rel ? blockIdx.x - blocks1 : blockIdx.x;
    const float* x = rel ? x2 : x1;
    const float* Wy = rel ? Wy2 : Wy1;
    const float* Ws = rel ? Ws2 : Ws1;
    _Float16* y = rel ? y2 : y1;
    float* s = rel ? s2 : s1;
    int N = rel ? N2 : N1;

    int gid = blk * 256 + threadIdx.x;
    int node = gid >> 5, od = gid & 31;
    if (node >= N) return;
    const float* xr = x + ((size_t)node << 6);
    float ay = 0.0f, as = 0.0f;
#pragma unroll
    for (int k = 0; k < 64; k++) {
        float xv = xr[k];
        ay += xv * Wy[(k << 5) + od];
        as += xv * Ws[(k << 5) + od];
    }
    y[((size_t)node << 5) + od] = (_Float16)ay;
    s[((size_t)node << 5) + od] = as;
}

// ---------------------------------------------------------------------------
// merged layer-1 pull (both relations): h = relu(b + s + mean_gather(y)),
// then immediately collapse to the layer-2 scalar: tgt[node] = h . v2
// (width-32 shuffle reduce). No h array is ever materialized.
__global__ void pull_l1_both(
    const int* __restrict__ ro_p, const int* __restrict__ ssp, const _Float16* __restrict__ y_c,
    const float* __restrict__ sp, const float* __restrict__ b_p, const float* __restrict__ hconst,
    float* __restrict__ u_p, int NP, int blocksP,
    const int* __restrict__ ro_c, const int* __restrict__ ssc, const _Float16* __restrict__ y_p,
    const float* __restrict__ sc_, const float* __restrict__ b_c, float* __restrict__ t_c, int NC) {
    int rel = blockIdx.x >= blocksP;
    int blk = rel ? blockIdx.x - blocksP : blockIdx.x;
    const int* ro = rel ? ro_c : ro_p;
    const int* ss = rel ? ssc : ssp;
    const _Float16* y = rel ? y_p : y_c;
    const float* sf = rel ? sc_ : sp;
    const float* bv = rel ? b_c : b_p;
    const float* v2 = rel ? hconst : hconst + 32;  // t_c uses v2l, u_p uses v2r
    float* tgt = rel ? t_c : u_p;
    int N = rel ? NC : NP;

    int gid = blk * 256 + threadIdx.x;
    int node = gid >> 5, od = gid & 31;
    if (node >= N) return;
    int start = ro[node], end = ro[node + 1];
    float acc = 0.0f;
    int j = start;
    for (; j + 3 < end; j += 4) {
        int a0 = ss[j], a1 = ss[j + 1], a2 = ss[j + 2], a3 = ss[j + 3];
        acc += (float)y[((size_t)a0 << 5) + od] + (float)y[((size_t)a1 << 5) + od]
             + (float)y[((size_t)a2 << 5) + od] + (float)y[((size_t)a3 << 5) + od];
    }
    for (; j < end; j++) acc += (float)y[((size_t)ss[j] << 5) + od];
    float r = bv[od] + sf[((size_t)node << 5) + od]
            + acc / fmaxf((float)(end - start), 1.0f);
    float p = fmaxf(r, 0.0f) * v2[od];
#pragma unroll
    for (int off = 16; off > 0; off >>= 1) p += __shfl_xor(p, off, 32);
    if (od == 0) tgt[node] = p;
}

// ---------------------------------------------------------------------------
// layer-2 scalar pull: logit = mean_{src in N(node)} t_c[src] + u_p[node]+cbias
// 4 threads/node, edge reads coalesced in groups of 4, scalar gathers (400KB table).
__global__ void pull_l2_scalar(const int* __restrict__ ro, const int* __restrict__ ss,
                               const float* __restrict__ t_c, const float* __restrict__ u_p,
                               const float* __restrict__ hconst,
                               float* __restrict__ out, int N) {
    int gid = blockIdx.x * blockDim.x + threadIdx.x;
    int node = gid >> 2, ln = gid & 3;
    if (node >= N) return;
    int s = ro[node], e = ro[node + 1];
    float acc = 0.0f;
    for (int j = s + ln; j < e; j += 4) acc += t_c[ss[j]];
    acc += __shfl_xor(acc, 1, 4);
    acc += __shfl_xor(acc, 2, 4);
    if (ln == 0) {
        float logit = acc / fmaxf((float)(e - s), 1.0f) + u_p[node] + hconst[64];
        out[node] = 1.0f / (1.0f + expf(-logit));
    }
}

// ---------------------------------------------------------------------------
extern "C" void kernel_launch(void* const* d_in, const int* in_sizes, int n_in,
                              void* d_out, int out_size, void* d_ws, size_t ws_size,
                              hipStream_t stream) {
    const float* xc    = (const float*)d_in[0];
    const float* xp    = (const float*)d_in[1];
    const int*   e_c2p = (const int*)d_in[2];   // src=cust, dst=prod
    const int*   e_p2c = (const int*)d_in[3];   // src=prod, dst=cust
    const float* W1l_r1 = (const float*)d_in[4];
    const float* b1_r1  = (const float*)d_in[5];
    const float* W1r_r1 = (const float*)d_in[6];
    const float* W1l_r2 = (const float*)d_in[7];
    const float* b1_r2  = (const float*)d_in[8];
    const float* W1r_r2 = (const float*)d_in[9];
    const float* W2l_r1 = (const float*)d_in[10];
    const float* b2_r1  = (const float*)d_in[11];
    const float* W2r_r1 = (const float*)d_in[12];
    const float* Wlin  = (const float*)d_in[16];
    const float* blin  = (const float*)d_in[17];
    float* out = (float*)d_out;

    const int NC = in_sizes[0] / 64;
    const int NP = in_sizes[1] / 64;
    const int E  = in_sizes[2] / 2;
    const int nbP = (NP + BSZ - 1) >> BB;
    const int nbC = (NC + BSZ - 1) >> BB;

    // ---- workspace layout ----
    char* w = (char*)d_ws;
    int* gcnt_p = (int*)w;  w += 256 * 4;
    int* gcnt_c = (int*)w;  w += 256 * 4;
    int* gcur_p = (int*)w;  w += 256 * 4;
    int* gcur_c = (int*)w;  w += 256 * 4;
    int* boff_p = (int*)w;  w += 257 * 4;
    int* boff_c = (int*)w;  w += 257 * 4;
    float* hconst = (float*)w; w += 68 * 4;
    w = (char*)(((uintptr_t)w + 255) & ~(uintptr_t)255);
    size_t szPair = (size_t)E * 4;
    if ((size_t)NP * 64 > szPair) szPair = (size_t)NP * 64;   // fp16 y fits pair buf
    if ((size_t)NC * 64 > szPair) szPair = (size_t)NC * 64;
    unsigned int* P_p = (unsigned int*)w;  w += szPair;   // later: y_c (fp16)
    unsigned int* P_c = (unsigned int*)w;  w += szPair;   // later: y_p (fp16)
    int* ss_p = (int*)w;    w += (size_t)E * 4;
    int* ss_c = (int*)w;    w += (size_t)E * 4;
    int* ro_p = (int*)w;    w += (size_t)(NP + 1) * 4;
    int* ro_c = (int*)w;    w += (size_t)(NC + 1) * 4;
    w = (char*)(((uintptr_t)w + 255) & ~(uintptr_t)255);
    float* s_p = (float*)w; w += (size_t)NP * 32 * 4;   // xp @ W1r_r1
    float* s_c = (float*)w; w += (size_t)NC * 32 * 4;   // xc @ W1r_r2
    float* t_c = (float*)w; w += (size_t)NC * 4;        // (h_c@W2l).Wlin scalar
    float* u_p = (float*)w; w += (size_t)NP * 4;        // (h_p@W2r).Wlin scalar
    _Float16* y_c = (_Float16*)P_p;   // alias (pairs dead after kbsort)
    _Float16* y_p = (_Float16*)P_c;

    const int bprH = (E + 8191) / 8192;
    const int bprB = (E + 4095) / 4096;

    // 1. zero bucket histograms + head constants (weights-only, runs early)
    fill_zero_i4<<<1, 128, 0, stream>>>((int4*)gcnt_p, 128);
    head_pre<<<1, 128, 0, stream>>>(W2l_r1, W2r_r1, b2_r1, Wlin, blin, hconst);

    // 2-5. CSR build
    khist<<<2 * bprH, 256, 0, stream>>>(e_c2p, e_p2c, E, gcnt_p, gcnt_c, nbP, nbC, bprH);
    kscan<<<2, 256, 0, stream>>>(gcnt_p, boff_p, gcur_p, nbP, gcnt_c, boff_c, gcur_c, nbC, E);
    kbin<<<2 * bprB, 256, 0, stream>>>(e_c2p, e_p2c, E, gcur_p, gcur_c, P_p, P_c, bprB);
    kbsort<<<nbP + nbC, 512, 0, stream>>>(P_p, P_c, boff_p, boff_c,
                                          ss_p, ss_c, ro_p, ro_c, NP, NC, nbP, nbC, E);

    // 6. fused projections (y fp16 + s fp32 in one pass over x; both types)
    //    NOTE: y_c/y_p alias P — must run after kbsort (stream-ordered, OK)
    const int blocksC = (NC * 32 + 255) / 256;
    const int blocksP = (NP * 32 + 255) / 256;
    proj_fused<<<blocksC + blocksP, 256, 0, stream>>>(
        xc, W1l_r1, W1r_r2, y_c, s_c, NC, blocksC,
        xp, W1l_r2, W1r_r1, y_p, s_p, NP);

    // 7. merged layer-1 pulls + scalar head collapse (writes t_c, u_p only)
    pull_l1_both<<<blocksP + blocksC, 256, 0, stream>>>(
        ro_p, ss_p, y_c, s_p, b1_r1, hconst, u_p, NP, blocksP,
        ro_c, ss_c, y_p, s_c, b1_r2, t_c, NC);

    // 8. layer-2 scalar pull + sigmoid (4B gathers from 400KB table)
    pull_l2_scalar<<<(NP * 4 + 255) / 256, 256, 0, stream>>>(
        ro_p, ss_p, t_c, u_p, hconst, out, NP);
}

// Round 7
// 301.755 us; speedup vs baseline: 1.8147x; 1.3682x over previous
//
#include <hip/hip_runtime.h>
#include <stdint.h>

#define BB 9            // bucket = dst >> 9 (512 dsts per bucket)
#define BSZ 512
#define STAGE_CAP 12288 // bucket edge capacity (mean ~8192, +45 sigma margin)

// ---------------------------------------------------------------------------
__global__ void fill_zero_i4(int4* __restrict__ p, size_t n4) {
    size_t i = (size_t)blockIdx.x * blockDim.x + threadIdx.x;
    size_t stride = (size_t)gridDim.x * blockDim.x;
    for (; i < n4; i += stride) p[i] = make_int4(0, 0, 0, 0);
}

// ---------------------------------------------------------------------------
// K1: coarse-bucket histogram, LDS-aggregated. Both relations in one grid.
__global__ void khist(const int* __restrict__ e1, const int* __restrict__ e2, int E,
                      int* __restrict__ gcnt1, int* __restrict__ gcnt2,
                      int nb1, int nb2, int blocksPerRel) {
    int rel = blockIdx.x >= blocksPerRel;
    int blk = rel ? blockIdx.x - blocksPerRel : blockIdx.x;
    const int* dst = (rel ? e2 : e1) + E;
    int* gcnt = rel ? gcnt2 : gcnt1;
    int nb = rel ? nb2 : nb1;
    __shared__ int cnt[256];
    for (int i = threadIdx.x; i < 256; i += 256) cnt[i] = 0;
    __syncthreads();
    int base = blk * 8192;
#pragma unroll
    for (int k = 0; k < 32; k++) {
        int i = base + k * 256 + threadIdx.x;
        if (i < E) atomicAdd(&cnt[dst[i] >> BB], 1);
    }
    __syncthreads();
    for (int b = threadIdx.x; b < nb; b += 256)
        if (cnt[b]) atomicAdd(&gcnt[b], cnt[b]);
}

// ---------------------------------------------------------------------------
// K2: exclusive scan of bucket counts (nb <= 256) -> boff[nb+1], gcur=boff.
__global__ void kscan(const int* __restrict__ gcnt1, int* __restrict__ boff1,
                      int* __restrict__ gcur1, int nb1,
                      const int* __restrict__ gcnt2, int* __restrict__ boff2,
                      int* __restrict__ gcur2, int nb2, int E) {
    const int* gcnt = blockIdx.x ? gcnt2 : gcnt1;
    int* boff = blockIdx.x ? boff2 : boff1;
    int* gcur = blockIdx.x ? gcur2 : gcur1;
    int nb = blockIdx.x ? nb2 : nb1;
    __shared__ int wsum[4];
    int tid = threadIdx.x, lane = tid & 63, wid = tid >> 6;
    int v = (tid < nb) ? gcnt[tid] : 0;
    int sc = v;
#pragma unroll
    for (int off = 1; off < 64; off <<= 1) {
        int t = __shfl_up(sc, off, 64);
        if (lane >= off) sc += t;
    }
    if (lane == 63) wsum[wid] = sc;
    __syncthreads();
    int woff = 0;
    for (int w = 0; w < wid; w++) woff += wsum[w];
    int excl = woff + sc - v;
    if (tid < nb) { boff[tid] = excl; gcur[tid] = excl; }
    if (tid == nb - 1) boff[nb] = excl + v;  // == E
}

// ---------------------------------------------------------------------------
// K3: bin edges into bucket regions (packed (src<<9 | dst&511) u32 runs).
__global__ void kbin(const int* __restrict__ e1, const int* __restrict__ e2, int E,
                     int* __restrict__ gcur1, int* __restrict__ gcur2,
                     unsigned int* __restrict__ P1, unsigned int* __restrict__ P2,
                     int blocksPerRel) {
    int rel = blockIdx.x >= blocksPerRel;
    int blk = rel ? blockIdx.x - blocksPerRel : blockIdx.x;
    const int* edge = rel ? e2 : e1;
    int* gcur = rel ? gcur2 : gcur1;
    unsigned int* P = rel ? P2 : P1;
    __shared__ int cnt[256];
    __shared__ int base[256];
    for (int i = threadIdx.x; i < 256; i += 256) cnt[i] = 0;
    __syncthreads();
    int cbase = blk * 4096;
    int src[16], dst[16], rk[16];
#pragma unroll
    for (int k = 0; k < 16; k++) {
        int i = cbase + k * 256 + threadIdx.x;
        if (i < E) {
            src[k] = edge[i];
            dst[k] = edge[E + i];
            rk[k] = atomicAdd(&cnt[dst[k] >> BB], 1);
        }
    }
    __syncthreads();
    for (int b = threadIdx.x; b < 256; b += 256)
        base[b] = cnt[b] ? atomicAdd(&gcur[b], cnt[b]) : 0;
    __syncthreads();
#pragma unroll
    for (int k = 0; k < 16; k++) {
        int i = cbase + k * 256 + threadIdx.x;
        if (i < E) {
            int b = dst[k] >> BB;
            P[base[b] + rk[k]] =
                ((unsigned)src[k] << BB) | (unsigned)(dst[k] & (BSZ - 1));
        }
    }
}

// ---------------------------------------------------------------------------
// K4: per-bucket counting sort in LDS -> sorted srcs + CSR row offsets.
__global__ void kbsort(const unsigned int* __restrict__ P1, const unsigned int* __restrict__ P2,
                       const int* __restrict__ boff1, const int* __restrict__ boff2,
                       int* __restrict__ ss1, int* __restrict__ ss2,
                       int* __restrict__ ro1, int* __restrict__ ro2,
                       int n1, int n2, int nb1, int nb2, int E) {
    int rel = blockIdx.x >= nb1;
    int b = rel ? blockIdx.x - nb1 : blockIdx.x;
    const unsigned int* P = rel ? P2 : P1;
    const int* boff = rel ? boff2 : boff1;
    int* ss = rel ? ss2 : ss1;
    int* ro = rel ? ro2 : ro1;
    int N = rel ? n2 : n1;
    int nb = rel ? nb2 : nb1;

    __shared__ int cnt[BSZ];
    __shared__ int cur[BSZ];
    __shared__ int wsum[8];
    __shared__ int stage[STAGE_CAP];

    int s = boff[b], e = boff[b + 1];
    int m = e - s;
    int d0 = b << BB;
    int nd = min(BSZ, N - d0);
    int tid = threadIdx.x;

    cnt[tid] = 0;
    __syncthreads();
    for (int i = tid; i < m; i += 512) atomicAdd(&cnt[P[s + i] & (BSZ - 1)], 1);
    __syncthreads();
    int lane = tid & 63, wid = tid >> 6;
    int v = cnt[tid], sc = v;
#pragma unroll
    for (int off = 1; off < 64; off <<= 1) {
        int t = __shfl_up(sc, off, 64);
        if (lane >= off) sc += t;
    }
    if (lane == 63) wsum[wid] = sc;
    __syncthreads();
    int woff = 0;
    for (int w = 0; w < wid; w++) woff += wsum[w];
    int excl = woff + sc - v;
    cur[tid] = excl;
    if (tid < nd) ro[d0 + tid] = s + excl;
    if (tid == 0 && b == nb - 1) ro[N] = E;
    __syncthreads();
    for (int i = tid; i < m; i += 512) {
        unsigned int p = P[s + i];
        int slot = atomicAdd(&cur[p & (BSZ - 1)], 1);
        if (slot < STAGE_CAP) stage[slot] = (int)(p >> BB);
    }
    __syncthreads();
    for (int i = tid; i < m; i += 512) ss[s + i] = stage[i];
}

// ---------------------------------------------------------------------------
// head precompute (D_OUT=1 collapse): v2l = W2l@Wlin, v2r = W2r@Wlin,
// cbias = b2.Wlin + blin.  hconst layout: [0..31]=v2l, [32..63]=v2r, [64]=cbias
__global__ void head_pre(const float* __restrict__ W2l, const float* __restrict__ W2r,
                         const float* __restrict__ b2, const float* __restrict__ Wlin,
                         const float* __restrict__ blin, float* __restrict__ hconst) {
    int t = threadIdx.x;
    if (t < 64) {
        const float* W = (t < 32) ? W2l : W2r;
        int k = t & 31;
        float acc = 0.0f;
#pragma unroll
        for (int j = 0; j < 32; j++) acc += W[k * 32 + j] * Wlin[j];
        hconst[t] = acc;
    }
    if (t == 64) {
        float acc = blin[0];
#pragma unroll
        for (int j = 0; j < 32; j++) acc += b2[j] * Wlin[j];
        hconst[64] = acc;
    }
}

// ---------------------------------------------------------------------------
// LDS-tiled fused projection: block handles 64 nodes; x tile + both W in LDS.
// Thread = (node, od-group of 8); computes y=x@Wy (fp16) and s=x@Ws (fp32).
__global__ void proj_tile(
    const float* __restrict__ x1, const float* __restrict__ Wy1, const float* __restrict__ Ws1,
    _Float16* __restrict__ y1, float* __restrict__ s1, int N1, int blocks1,
    const float* __restrict__ x2, const float* __restrict__ Wy2, const float* __restrict__ Ws2,
    _Float16* __restrict__ y2, float* __restrict__ s2, int N2) {
    int rel = blockIdx.x >= blocks1;
    int blk = rel ? blockIdx.x - blocks1 : blockIdx.x;
    const float* x = rel ? x2 : x1;
    const float* Wy = rel ? Wy2 : Wy1;
    const float* Ws = rel ? Ws2 : Ws1;
    _Float16* y = rel ? y2 : y1;
    float* s = rel ? s2 : s1;
    int N = rel ? N2 : N1;

    __shared__ float xs[64][68];      // +4 pad keeps 16B alignment, spreads banks
    __shared__ float wyl[64][32];
    __shared__ float wsl[64][32];

    int tid = threadIdx.x;
    // stage W (2048 floats each = 512 float4; 2 per thread each)
    {
        const float4* a = (const float4*)Wy;
        const float4* b = (const float4*)Ws;
        float4* la = (float4*)&wyl[0][0];
        float4* lb = (float4*)&wsl[0][0];
        la[tid] = a[tid];
        la[tid + 256] = a[tid + 256];
        lb[tid] = b[tid];
        lb[tid + 256] = b[tid + 256];
    }
    // stage x tile: 64 rows x 16 float4 (fully coalesced)
    int base = blk << 6;
#pragma unroll
    for (int i = 0; i < 4; i++) {
        int idx = i * 256 + tid;            // 0..1023
        int row = idx >> 4, c4 = (idx & 15) << 2;
        int node = base + row;
        float4 v = (node < N) ? *(const float4*)(x + ((size_t)node << 6) + c4)
                              : make_float4(0.f, 0.f, 0.f, 0.f);
        *(float4*)&xs[row][c4] = v;
    }
    __syncthreads();

    int node = tid & 63;
    int ob = (tid >> 6) << 3;               // od base (wave-uniform)
    float ay[8] = {0,0,0,0,0,0,0,0};
    float as_[8] = {0,0,0,0,0,0,0,0};
#pragma unroll
    for (int kc = 0; kc < 16; kc++) {
        float4 xv = *(float4*)&xs[node][kc << 2];
#pragma unroll
        for (int kk = 0; kk < 4; kk++) {
            int k = (kc << 2) + kk;
            float xk = (kk == 0) ? xv.x : (kk == 1) ? xv.y : (kk == 2) ? xv.z : xv.w;
            float4 a = *(float4*)&wyl[k][ob];
            float4 b = *(float4*)&wyl[k][ob + 4];
            float4 c = *(float4*)&wsl[k][ob];
            float4 d = *(float4*)&wsl[k][ob + 4];
            ay[0] += xk * a.x; ay[1] += xk * a.y; ay[2] += xk * a.z; ay[3] += xk * a.w;
            ay[4] += xk * b.x; ay[5] += xk * b.y; ay[6] += xk * b.z; ay[7] += xk * b.w;
            as_[0] += xk * c.x; as_[1] += xk * c.y; as_[2] += xk * c.z; as_[3] += xk * c.w;
            as_[4] += xk * d.x; as_[5] += xk * d.y; as_[6] += xk * d.z; as_[7] += xk * d.w;
        }
    }
    int ng = base + node;
    if (ng < N) {
        union { _Float16 h[8]; uint4 v; } u;
#pragma unroll
        for (int j = 0; j < 8; j++) u.h[j] = (_Float16)ay[j];
        *(uint4*)(y + ((size_t)ng << 5) + ob) = u.v;
        *(float4*)(s + ((size_t)ng << 5) + ob) =
            make_float4(as_[0], as_[1], as_[2], as_[3]);
        *(float4*)(s + ((size_t)ng << 5) + ob + 4) =
            make_float4(as_[4], as_[5], as_[6], as_[7]);
    }
}

// ---------------------------------------------------------------------------
// merged layer-1 pull (both relations): h = relu(b + s + mean_gather(y)),
// then collapse to the layer-2 scalar: tgt[node] = h . v2 (shuffle reduce).
__global__ void pull_l1_both(
    const int* __restrict__ ro_p, const int* __restrict__ ssp, const _Float16* __restrict__ y_c,
    const float* __restrict__ sp, const float* __restrict__ b_p, const float* __restrict__ hconst,
    float* __restrict__ u_p, int NP, int blocksP,
    const int* __restrict__ ro_c, const int* __restrict__ ssc, const _Float16* __restrict__ y_p,
    const float* __restrict__ sc_, const float* __restrict__ b_c, float* __restrict__ t_c, int NC) {
    int rel = blockIdx.x >= blocksP;
    int blk = rel ? blockIdx.x - blocksP : blockIdx.x;
    const int* ro = rel ? ro_c : ro_p;
    const int* ss = rel ? ssc : ssp;
    const _Float16* y = rel ? y_p : y_c;
    const float* sf = rel ? sc_ : sp;
    const float* bv = rel ? b_c : b_p;
    const float* v2 = rel ? hconst : hconst + 32;  // t_c uses v2l, u_p uses v2r
    float* tgt = rel ? t_c : u_p;
    int N = rel ? NC : NP;

    int gid = blk * 256 + threadIdx.x;
    int node = gid >> 5, od = gid & 31;
    if (node >= N) return;
    int start = ro[node], end = ro[node + 1];
    float acc = 0.0f;
    int j = start;
    for (; j + 3 < end; j += 4) {
        int a0 = ss[j], a1 = ss[j + 1], a2 = ss[j + 2], a3 = ss[j + 3];
        acc += (float)y[((size_t)a0 << 5) + od] + (float)y[((size_t)a1 << 5) + od]
             + (float)y[((size_t)a2 << 5) + od] + (float)y[((size_t)a3 << 5) + od];
    }
    for (; j < end; j++) acc += (float)y[((size_t)ss[j] << 5) + od];
    float r = bv[od] + sf[((size_t)node << 5) + od]
            + acc / fmaxf((float)(end - start), 1.0f);
    float p = fmaxf(r, 0.0f) * v2[od];
#pragma unroll
    for (int off = 16; off > 0; off >>= 1) p += __shfl_xor(p, off, 32);
    if (od == 0) tgt[node] = p;
}

// ---------------------------------------------------------------------------
// layer-2 scalar pull: logit = mean_{src in N(node)} t_c[src] + u_p[node]+cbias
__global__ void pull_l2_scalar(const int* __restrict__ ro, const int* __restrict__ ss,
                               const float* __restrict__ t_c, const float* __restrict__ u_p,
                               const float* __restrict__ hconst,
                               float* __restrict__ out, int N) {
    int gid = blockIdx.x * blockDim.x + threadIdx.x;
    int node = gid >> 2, ln = gid & 3;
    if (node >= N) return;
    int s = ro[node], e = ro[node + 1];
    float acc = 0.0f;
    for (int j = s + ln; j < e; j += 4) acc += t_c[ss[j]];
    acc += __shfl_xor(acc, 1, 4);
    acc += __shfl_xor(acc, 2, 4);
    if (ln == 0) {
        float logit = acc / fmaxf((float)(e - s), 1.0f) + u_p[node] + hconst[64];
        out[node] = 1.0f / (1.0f + expf(-logit));
    }
}

// ---------------------------------------------------------------------------
extern "C" void kernel_launch(void* const* d_in, const int* in_sizes, int n_in,
                              void* d_out, int out_size, void* d_ws, size_t ws_size,
                              hipStream_t stream) {
    const float* xc    = (const float*)d_in[0];
    const float* xp    = (const float*)d_in[1];
    const int*   e_c2p = (const int*)d_in[2];   // src=cust, dst=prod
    const int*   e_p2c = (const int*)d_in[3];   // src=prod, dst=cust
    const float* W1l_r1 = (const float*)d_in[4];
    const float* b1_r1  = (const float*)d_in[5];
    const float* W1r_r1 = (const float*)d_in[6];
    const float* W1l_r2 = (const float*)d_in[7];
    const float* b1_r2  = (const float*)d_in[8];
    const float* W1r_r2 = (const float*)d_in[9];
    const float* W2l_r1 = (const float*)d_in[10];
    const float* b2_r1  = (const float*)d_in[11];
    const float* W2r_r1 = (const float*)d_in[12];
    const float* Wlin  = (const float*)d_in[16];
    const float* blin  = (const float*)d_in[17];
    float* out = (float*)d_out;

    const int NC = in_sizes[0] / 64;
    const int NP = in_sizes[1] / 64;
    const int E  = in_sizes[2] / 2;
    const int nbP = (NP + BSZ - 1) >> BB;
    const int nbC = (NC + BSZ - 1) >> BB;

    // ---- workspace layout ----
    char* w = (char*)d_ws;
    int* gcnt_p = (int*)w;  w += 256 * 4;
    int* gcnt_c = (int*)w;  w += 256 * 4;
    int* gcur_p = (int*)w;  w += 256 * 4;
    int* gcur_c = (int*)w;  w += 256 * 4;
    int* boff_p = (int*)w;  w += 257 * 4;
    int* boff_c = (int*)w;  w += 257 * 4;
    float* hconst = (float*)w; w += 68 * 4;
    w = (char*)(((uintptr_t)w + 255) & ~(uintptr_t)255);
    size_t szPair = (size_t)E * 4;
    if ((size_t)NP * 64 > szPair) szPair = (size_t)NP * 64;   // fp16 y fits pair buf
    if ((size_t)NC * 64 > szPair) szPair = (size_t)NC * 64;
    unsigned int* P_p = (unsigned int*)w;  w += szPair;   // later: y_c (fp16)
    unsigned int* P_c = (unsigned int*)w;  w += szPair;   // later: y_p (fp16)
    int* ss_p = (int*)w;    w += (size_t)E * 4;
    int* ss_c = (int*)w;    w += (size_t)E * 4;
    int* ro_p = (int*)w;    w += (size_t)(NP + 1) * 4;
    int* ro_c = (int*)w;    w += (size_t)(NC + 1) * 4;
    w = (char*)(((uintptr_t)w + 255) & ~(uintptr_t)255);
    float* s_p = (float*)w; w += (size_t)NP * 32 * 4;   // xp @ W1r_r1
    float* s_c = (float*)w; w += (size_t)NC * 32 * 4;   // xc @ W1r_r2
    float* t_c = (float*)w; w += (size_t)NC * 4;        // (h_c@W2l).Wlin scalar
    float* u_p = (float*)w; w += (size_t)NP * 4;        // (h_p@W2r).Wlin scalar
    _Float16* y_c = (_Float16*)P_p;   // alias (pairs dead after kbsort)
    _Float16* y_p = (_Float16*)P_c;

    const int bprH = (E + 8191) / 8192;
    const int bprB = (E + 4095) / 4096;

    // 1. zero bucket histograms + head constants
    fill_zero_i4<<<1, 128, 0, stream>>>((int4*)gcnt_p, 128);
    head_pre<<<1, 128, 0, stream>>>(W2l_r1, W2r_r1, b2_r1, Wlin, blin, hconst);

    // 2-5. CSR build
    khist<<<2 * bprH, 256, 0, stream>>>(e_c2p, e_p2c, E, gcnt_p, gcnt_c, nbP, nbC, bprH);
    kscan<<<2, 256, 0, stream>>>(gcnt_p, boff_p, gcur_p, nbP, gcnt_c, boff_c, gcur_c, nbC, E);
    kbin<<<2 * bprB, 256, 0, stream>>>(e_c2p, e_p2c, E, gcur_p, gcur_c, P_p, P_c, bprB);
    kbsort<<<nbP + nbC, 512, 0, stream>>>(P_p, P_c, boff_p, boff_c,
                                          ss_p, ss_c, ro_p, ro_c, NP, NC, nbP, nbC, E);

    // 6. LDS-tiled fused projections (y fp16 + s fp32; both node types)
    //    NOTE: y_c/y_p alias P — must run after kbsort (stream-ordered, OK)
    const int tblocksC = (NC + 63) / 64;
    const int tblocksP = (NP + 63) / 64;
    proj_tile<<<tblocksC + tblocksP, 256, 0, stream>>>(
        xc, W1l_r1, W1r_r2, y_c, s_c, NC, tblocksC,
        xp, W1l_r2, W1r_r1, y_p, s_p, NP);

    // 7. merged layer-1 pulls + scalar head collapse (writes t_c, u_p only)
    const int blocksP = (NP * 32 + 255) / 256;
    const int blocksC = (NC * 32 + 255) / 256;
    pull_l1_both<<<blocksP + blocksC, 256, 0, stream>>>(
        ro_p, ss_p, y_c, s_p, b1_r1, hconst, u_p, NP, blocksP,
        ro_c, ss_c, y_p, s_c, b1_r2, t_c, NC);

    // 8. layer-2 scalar pull + sigmoid (4B gathers from 400KB table)
    pull_l2_scalar<<<(NP * 4 + 255) / 256, 256, 0, stream>>>(
        ro_p, ss_p, t_c, u_p, hconst, out, NP);
}